// Round 2
// baseline (2843.130 us; speedup 1.0000x reference)
//
#include <hip/hip_runtime.h>
#include <hip/hip_fp16.h>
#include <stdint.h>

// ---------------------------------------------------------------------------
// StateRNN: masked LSTM (B=64,T=2048,H=256) + 3-layer MLP head.
// Strategy: mask-segmented recurrence (phase1 parallel-from-first-reset,
// phase2 sequential prefix fill), f16 weights resident in VGPR+LDS per CU,
// f16 dot2 arithmetic with f32 accumulate, fused f16 MLP head.
//
// R1 fixes vs R0 (desk-check, no HW yet):
//  * hs buffer is now TIME-MAJOR [T,B,H]. The reference reshapes [T,B,H] ->
//    [T*B,H] -> head -> reshape [B,T,32]; flat row i = (t=i/B, b=i%B). The
//    batch-major layout in R0 permuted the output rows -> would fail check.
//  * phase1: __syncthreads() after reading s_r (continue path raced with the
//    next task's ballot write).
// ---------------------------------------------------------------------------

typedef _Float16 f16;
typedef _Float16 f16x2 __attribute__((ext_vector_type(2)));
typedef unsigned int u32;
typedef u32 u32x2 __attribute__((ext_vector_type(2)));
typedef u32 u32x4 __attribute__((ext_vector_type(4)));
typedef float f32x4 __attribute__((ext_vector_type(4)));

#define B_     64
#define T_     2048
#define NIN_   48
#define H_     256
#define G4_    1024
#define CH_    64               // chunk length (== wave size, used by ballot scan)
#define NCHUNK (T_ / CH_)       // 32
#define NTASK  (B_ * NCHUNK)    // 2048
#define P1_WG  256
#define P1_TPW (NTASK / P1_WG)  // 8
#define NROWS  (B_ * T_)        // 131072

__device__ __forceinline__ f16x2 as_h2(u32 u) { return __builtin_bit_cast(f16x2, u); }

__device__ __forceinline__ float dot2(u32 a, u32 b, float c) {
#if __has_builtin(__builtin_amdgcn_fdot2)
  return __builtin_amdgcn_fdot2(as_h2(a), as_h2(b), c, false);
#else
  f16x2 ah = as_h2(a), bh = as_h2(b);
  return c + (float)ah.x * (float)bh.x + (float)ah.y * (float)bh.y;
#endif
}

__device__ __forceinline__ float dot8(u32x4 a, u32x4 b, float acc) {
  acc = dot2(a.x, b.x, acc);
  acc = dot2(a.y, b.y, acc);
  acc = dot2(a.z, b.z, acc);
  acc = dot2(a.w, b.w, acc);
  return acc;
}

// load 16B from LDS via two 8B reads (for stride-padded layouts not 16B aligned)
__device__ __forceinline__ u32x4 ld2x64(const f16* p) {
  u32x2 a = *(const u32x2*)p;
  u32x2 b = *(const u32x2*)(p + 4);
  u32x4 r; r.x = a.x; r.y = a.y; r.z = b.x; r.w = b.y;
  return r;
}

// acc += sum_k x[k] * (float)w[k]  (8 wide, mixed f32*f16)
__device__ __forceinline__ float mix8(f32x4 x0, f32x4 x1, u32x4 wv, float acc) {
  f16x2 p;
  p = as_h2(wv.x); acc = fmaf((float)p.x, x0.x, acc); acc = fmaf((float)p.y, x0.y, acc);
  p = as_h2(wv.y); acc = fmaf((float)p.x, x0.z, acc); acc = fmaf((float)p.y, x0.w, acc);
  p = as_h2(wv.z); acc = fmaf((float)p.x, x1.x, acc); acc = fmaf((float)p.y, x1.y, acc);
  p = as_h2(wv.w); acc = fmaf((float)p.x, x1.z, acc); acc = fmaf((float)p.y, x1.w, acc);
  return acc;
}

__device__ __forceinline__ float sigmf(float x) {
  return 1.0f / (1.0f + __builtin_exp2f(-1.44269504f * x));
}
__device__ __forceinline__ float tanhf_(float x) {
  return 2.0f / (1.0f + __builtin_exp2f(-2.88539008f * x)) - 1.0f;
}

// ---------------------------------------------------------------------------
// K0: convert weights to f16, transposed where needed.
// wxT[c][k] (1024x48), whT[c][k] (1024x256), w1T[o][k] (256x256),
// w2T[o][k] (128x256), w3T[o][k] (32x128)
// ---------------------------------------------------------------------------
__global__ void k_prep(const float* __restrict__ wx, const float* __restrict__ wh,
                       const float* __restrict__ w1, const float* __restrict__ w2,
                       const float* __restrict__ w3,
                       f16* __restrict__ wxT, f16* __restrict__ whT,
                       f16* __restrict__ w1T, f16* __restrict__ w2T,
                       f16* __restrict__ w3T) {
  const int i0 = blockIdx.x * blockDim.x + threadIdx.x;
  const int stride = gridDim.x * blockDim.x;
  for (int idx = i0; idx < NIN_ * G4_; idx += stride) {
    int k = idx / G4_, c = idx % G4_;
    wxT[c * NIN_ + k] = (f16)wx[idx];
  }
  for (int idx = i0; idx < H_ * G4_; idx += stride) {
    int k = idx / G4_, c = idx % G4_;
    whT[c * H_ + k] = (f16)wh[idx];
  }
  for (int idx = i0; idx < 256 * 256; idx += stride) {
    int k = idx / 256, o = idx % 256;
    w1T[o * 256 + k] = (f16)w1[idx];
  }
  for (int idx = i0; idx < 256 * 128; idx += stride) {
    int k = idx / 128, o = idx % 128;
    w2T[o * 256 + k] = (f16)w2[idx];
  }
  for (int idx = i0; idx < 128 * 32; idx += stride) {
    int k = idx / 32, o = idx % 32;
    w3T[o * 128 + k] = (f16)w3[idx];
  }
}

// ---------------------------------------------------------------------------
// Phase 1: 256 WGs x 512 threads. Each WG: full wh f16 resident
// (192 VGPRs/thread packed + 128KB LDS). 8 tasks per WG; per task:
// find first reset r; if none, skip (phase2 handles). Else compute inline
// xw chunk (x@wx+b -> per-WG global scratch), then steps [r,64) from zero.
// Thread t: unit j = t>>1, k-half q = t&1. Per step: 256 f16 MACs via dot2,
// pair shfl reduce, gate math, h broadcast via LDS (double buffered).
// hs is written TIME-MAJOR: hs[(t*B + b)*H + j].
// ---------------------------------------------------------------------------
__global__ __launch_bounds__(512, 2) void k_phase1(
    const float* __restrict__ seq, const float* __restrict__ mask,
    const f16* __restrict__ wxT, const f16* __restrict__ whT,
    const float* __restrict__ bias,
    f16* __restrict__ xw_ws, f16* __restrict__ hs, float* __restrict__ carry) {
  __shared__ __attribute__((aligned(16))) u32x4 s_w[4 * 4 * 512];  // 128KB lds-resident weights
  __shared__ __attribute__((aligned(16))) f16 s_h[2][H_];          // h double buffer
  __shared__ __attribute__((aligned(16))) f16 s_x[CH_ * NIN_];     // x chunk (f16)
  __shared__ int s_r;

  const int tid = threadIdx.x;
  const int j = tid >> 1, q = tid & 1;

  // --- load resident weights: per thread 4 gates x 128 k (96 reg + 32 lds)
  u32x4 wreg[4][12];
#pragma unroll
  for (int g = 0; g < 4; ++g) {
    const f16* wp = whT + (size_t)(g * H_ + j) * H_ + q * 128;
#pragma unroll
    for (int kb = 0; kb < 12; ++kb) wreg[g][kb] = *(const u32x4*)(wp + kb * 8);
#pragma unroll
    for (int kb = 0; kb < 4; ++kb)
      s_w[(g * 4 + kb) * 512 + tid] = *(const u32x4*)(wp + 96 + kb * 8);
  }
  __syncthreads();

  f16* xwp = xw_ws + (size_t)blockIdx.x * (CH_ * G4_);

  for (int task = 0; task < P1_TPW; ++task) {
    const int gtask = blockIdx.x * P1_TPW + task;
    const int b = gtask >> 5, ch = gtask & 31;
    const int t0 = ch * CH_;

    // --- first reset position in chunk (wave 0 ballot)
    if (tid < 64) {
      float mv = mask[b * T_ + t0 + tid];
      unsigned long long bal = __ballot(mv != 0.0f);
      if (tid == 0) s_r = bal ? (__ffsll((unsigned long long)bal) - 1) : CH_;
    }
    __syncthreads();
    const int r = s_r;
    __syncthreads();  // R1 fix: all threads read s_r before next task's ballot rewrites it
    if (r >= CH_) continue;  // uniform: no reset -> phase2 computes whole chunk

    // --- stage x chunk as f16 (flat copy)
    {
      const float* sp = seq + ((size_t)b * T_ + t0) * NIN_;
      for (int i = tid; i < CH_ * NIN_; i += 512) s_x[i] = (f16)sp[i];
    }
    if (tid < H_) { s_h[0][tid] = (f16)0.f; s_h[1][tid] = (f16)0.f; }
    __syncthreads();

    // --- xw chunk GEMM: [64,48]@[48,1024] + bias -> xwp (f16). cols {2t,2t+1}
    {
      const int c0 = tid * 2;
      const float bia0 = bias[c0], bia1 = bias[c0 + 1];
      for (int tt = 0; tt < 8; ++tt) {
        float acc0[8], acc1[8];
#pragma unroll
        for (int rr = 0; rr < 8; ++rr) { acc0[rr] = 0.f; acc1[rr] = 0.f; }
#pragma unroll
        for (int kb = 0; kb < 6; ++kb) {
          u32x4 w0 = *(const u32x4*)(wxT + c0 * NIN_ + kb * 8);
          u32x4 w1 = *(const u32x4*)(wxT + (c0 + 1) * NIN_ + kb * 8);
#pragma unroll
          for (int rr = 0; rr < 8; ++rr) {
            u32x4 xv = *(const u32x4*)(&s_x[(tt * 8 + rr) * NIN_ + kb * 8]);
            acc0[rr] = dot8(xv, w0, acc0[rr]);
            acc1[rr] = dot8(xv, w1, acc1[rr]);
          }
        }
#pragma unroll
        for (int rr = 0; rr < 8; ++rr) {
          f16x2 o2;
          o2.x = (f16)(acc0[rr] + bia0);
          o2.y = (f16)(acc1[rr] + bia1);
          *(f16x2*)(xwp + (tt * 8 + rr) * G4_ + c0) = o2;
        }
      }
    }
    __threadfence_block();
    float c_state = 0.f, h_last = 0.f;
    __syncthreads();

    // --- recurrent steps [t0+r, t0+64)
    for (int t = t0 + r; t < t0 + CH_; ++t) {
      const float m = mask[b * T_ + t];
      const int par = t & 1;
      float acc[4] = {0.f, 0.f, 0.f, 0.f};
      const f16* hrow = &s_h[par][q * 128];
#pragma unroll
      for (int kb = 0; kb < 12; ++kb) {
        u32x4 hv = *(const u32x4*)(hrow + kb * 8);
#pragma unroll
        for (int g = 0; g < 4; ++g) acc[g] = dot8(hv, wreg[g][kb], acc[g]);
      }
#pragma unroll
      for (int kb = 0; kb < 4; ++kb) {
        u32x4 hv = *(const u32x4*)(hrow + 96 + kb * 8);
#pragma unroll
        for (int g = 0; g < 4; ++g)
          acc[g] = dot8(hv, s_w[(g * 4 + kb) * 512 + tid], acc[g]);
      }
#pragma unroll
      for (int g = 0; g < 4; ++g) acc[g] += __shfl_xor(acc[g], 1);

      const float keep = 1.0f - m;  // mask: state zeroed before step when m==1
      const f16* xr = xwp + (t - t0) * G4_;
      float z0 = (float)xr[j] + keep * acc[0];
      float z1 = (float)xr[H_ + j] + keep * acc[1];
      float z2 = (float)xr[2 * H_ + j] + keep * acc[2];
      float z3 = (float)xr[3 * H_ + j] + keep * acc[3];
      float ig = sigmf(z0), fg = sigmf(z1), og = sigmf(z2), ug = tanhf_(z3);
      c_state = fg * (keep * c_state) + ig * ug;
      const float hn = og * tanhf_(c_state);
      h_last = hn;
      if (q == 0) {
        s_h[par ^ 1][j] = (f16)hn;
        hs[((size_t)t * B_ + b) * H_ + j] = (f16)hn;  // time-major
      }
      __syncthreads();
    }
    if (q == 0) {
      carry[(size_t)gtask * 512 + j] = c_state;
      carry[(size_t)gtask * 512 + H_ + j] = h_last;
    }
  }
}

// ---------------------------------------------------------------------------
// Phase 2: 64 WGs (one per batch row). Sequential walk over chunks filling
// prefixes [t0, t0+r) from the true carry; adopt phase-1 carry afterwards.
// xw computed inline (x row staged, wxT from L2). Writes states_out.
// Note: prefix steps have mask==0 by construction of r.
// hs written TIME-MAJOR.
// ---------------------------------------------------------------------------
__global__ __launch_bounds__(512, 2) void k_phase2(
    const float* __restrict__ seq, const float* __restrict__ mask,
    const float* __restrict__ states_in,
    const f16* __restrict__ wxT, const f16* __restrict__ whT,
    const float* __restrict__ bias,
    const float* __restrict__ carry,
    f16* __restrict__ hs, float* __restrict__ out_states) {
  __shared__ __attribute__((aligned(16))) u32x4 s_w[4 * 4 * 512];
  __shared__ __attribute__((aligned(16))) f16 s_h[H_];
  __shared__ __attribute__((aligned(16))) float s_x48[NIN_];
  __shared__ int s_r;

  const int tid = threadIdx.x;
  const int j = tid >> 1, q = tid & 1;
  const int b = blockIdx.x;

  u32x4 wreg[4][12];
#pragma unroll
  for (int g = 0; g < 4; ++g) {
    const f16* wp = whT + (size_t)(g * H_ + j) * H_ + q * 128;
#pragma unroll
    for (int kb = 0; kb < 12; ++kb) wreg[g][kb] = *(const u32x4*)(wp + kb * 8);
#pragma unroll
    for (int kb = 0; kb < 4; ++kb)
      s_w[(g * 4 + kb) * 512 + tid] = *(const u32x4*)(wp + 96 + kb * 8);
  }
  if (tid < H_) s_h[tid] = (f16)states_in[b * 512 + H_ + tid];
  float c_state = states_in[b * 512 + j];
  float h_cur = states_in[b * 512 + H_ + j];
  const float bia[4] = {bias[j], bias[H_ + j], bias[2 * H_ + j], bias[3 * H_ + j]};
  __syncthreads();

  for (int ch = 0; ch < NCHUNK; ++ch) {
    const int t0 = ch * CH_;
    if (tid < 64) {
      float mv = mask[b * T_ + t0 + tid];
      unsigned long long bal = __ballot(mv != 0.0f);
      if (tid == 0) s_r = bal ? (__ffsll((unsigned long long)bal) - 1) : CH_;
    }
    __syncthreads();
    const int r = s_r;

    for (int t = t0; t < t0 + r; ++t) {  // prefix (mask==0 on all these steps)
      if (tid < NIN_) s_x48[tid] = seq[((size_t)b * T_ + t) * NIN_ + tid];
      __syncthreads();
      float acc[4] = {0.f, 0.f, 0.f, 0.f};
      const f16* hrow = &s_h[q * 128];
#pragma unroll
      for (int kb = 0; kb < 12; ++kb) {
        u32x4 hv = *(const u32x4*)(hrow + kb * 8);
#pragma unroll
        for (int g = 0; g < 4; ++g) acc[g] = dot8(hv, wreg[g][kb], acc[g]);
      }
#pragma unroll
      for (int kb = 0; kb < 4; ++kb) {
        u32x4 hv = *(const u32x4*)(hrow + 96 + kb * 8);
#pragma unroll
        for (int g = 0; g < 4; ++g)
          acc[g] = dot8(hv, s_w[(g * 4 + kb) * 512 + tid], acc[g]);
      }
      // inline xw: this thread's q-half of k=48 (24 values)
#pragma unroll
      for (int kb = 0; kb < 3; ++kb) {
        f32x4 x0 = *(const f32x4*)(s_x48 + q * 24 + kb * 8);
        f32x4 x1 = *(const f32x4*)(s_x48 + q * 24 + kb * 8 + 4);
#pragma unroll
        for (int g = 0; g < 4; ++g) {
          u32x4 wv = *(const u32x4*)(wxT + (size_t)(g * H_ + j) * NIN_ + q * 24 + kb * 8);
          acc[g] = mix8(x0, x1, wv, acc[g]);
        }
      }
#pragma unroll
      for (int g = 0; g < 4; ++g) acc[g] += __shfl_xor(acc[g], 1);
      float z0 = acc[0] + bia[0], z1 = acc[1] + bia[1];
      float z2 = acc[2] + bia[2], z3 = acc[3] + bia[3];
      float ig = sigmf(z0), fg = sigmf(z1), og = sigmf(z2), ug = tanhf_(z3);
      c_state = fg * c_state + ig * ug;
      const float hn = og * tanhf_(c_state);
      h_cur = hn;
      __syncthreads();  // all k-loop reads of s_h done before overwrite
      if (q == 0) {
        s_h[j] = (f16)hn;
        hs[((size_t)t * B_ + b) * H_ + j] = (f16)hn;  // time-major
      }
      __syncthreads();
    }

    if (r < CH_) {  // adopt the exact phase-1 carry for this chunk's end state
      const int gtask = b * NCHUNK + ch;
      c_state = carry[(size_t)gtask * 512 + j];
      h_cur = carry[(size_t)gtask * 512 + H_ + j];
      __syncthreads();
      if (tid < H_) s_h[tid] = (f16)carry[(size_t)gtask * 512 + H_ + tid];
      __syncthreads();
    }
  }
  if (q == 0) {
    out_states[b * 512 + j] = c_state;
    out_states[b * 512 + H_ + j] = h_cur;
  }
}

// ---------------------------------------------------------------------------
// Head: fused 3-layer MLP over 32-row tiles of the flat [T*B, H] hidden
// buffer (time-major, matching the reference's reshape semantics).
// d1=relu(hs@w1+b1); d2=relu(d1@w2+b2); out=d2@w3+b3.
// Weight chunks staged to LDS with stride-20 padding (kills 32-way conflict).
// ---------------------------------------------------------------------------
#define K3R 32
__global__ __launch_bounds__(256, 2) void k_head(
    const f16* __restrict__ hs,
    const f16* __restrict__ w1T, const float* __restrict__ b1,
    const f16* __restrict__ w2T, const float* __restrict__ b2,
    const f16* __restrict__ w3T, const float* __restrict__ b3,
    float* __restrict__ out) {
  __shared__ __attribute__((aligned(16))) f16 s_xx[K3R * 256];   // 16KB
  __shared__ __attribute__((aligned(16))) f16 s_d1[K3R * 256];   // 16KB
  __shared__ __attribute__((aligned(16))) f16 s_d2[K3R * 128];   // 8KB
  __shared__ __attribute__((aligned(16))) f16 s_wst[256 * 20];   // 10KB padded stage
  __shared__ __attribute__((aligned(16))) f16 s_w3[32 * 136];    // padded
  __shared__ float s_b1[256];
  __shared__ float s_b2[128];
  __shared__ float s_b3[32];

  const int tid = threadIdx.x;
  const size_t row0 = (size_t)blockIdx.x * K3R;

  {
    const u32x4* src = (const u32x4*)(hs + row0 * 256);
    u32x4* dst = (u32x4*)s_xx;
    for (int i = tid; i < K3R * 256 / 8; i += 256) dst[i] = src[i];
  }
  for (int i = tid; i < 32 * 128; i += 256) {
    int c = i / 128, k = i % 128;
    s_w3[c * 136 + k] = w3T[i];
  }
  if (tid < 256) s_b1[tid] = b1[tid];
  if (tid < 128) s_b2[tid] = b2[tid];
  if (tid < 32) s_b3[tid] = b3[tid];

  // ---- L1: [32,256] @ [256->256]
  {
    const int rb = tid >> 5;  // 8 row blocks x4
    const int cb = tid & 31;  // 32 col blocks x8
    float acc[4][8];
#pragma unroll
    for (int rr = 0; rr < 4; ++rr)
#pragma unroll
      for (int cc = 0; cc < 8; ++cc) acc[rr][cc] = 0.f;
    for (int ks = 0; ks < 16; ++ks) {
      __syncthreads();
      {  // stage w1T[:, ks*16..+16] -> s_wst, stride 20
        const u32x4* wsrc = (const u32x4*)(w1T + (size_t)tid * 256 + ks * 16);
        u32x2* wdst = (u32x2*)(s_wst + tid * 20);
        u32x4 a = wsrc[0], b = wsrc[1];
        u32x2 p0; p0.x = a.x; p0.y = a.y;
        u32x2 p1; p1.x = a.z; p1.y = a.w;
        u32x2 p2; p2.x = b.x; p2.y = b.y;
        u32x2 p3; p3.x = b.z; p3.y = b.w;
        wdst[0] = p0; wdst[1] = p1; wdst[2] = p2; wdst[3] = p3;
      }
      __syncthreads();
#pragma unroll
      for (int kb = 0; kb < 2; ++kb) {
        u32x4 xv[4];
#pragma unroll
        for (int rr = 0; rr < 4; ++rr)
          xv[rr] = *(const u32x4*)(s_xx + (rb * 4 + rr) * 256 + ks * 16 + kb * 8);
#pragma unroll
        for (int cc = 0; cc < 8; ++cc) {
          u32x4 wv = ld2x64(s_wst + (cb * 8 + cc) * 20 + kb * 8);
#pragma unroll
          for (int rr = 0; rr < 4; ++rr) acc[rr][cc] = dot8(xv[rr], wv, acc[rr][cc]);
        }
      }
    }
    __syncthreads();
#pragma unroll
    for (int rr = 0; rr < 4; ++rr)
#pragma unroll
      for (int cc = 0; cc < 8; ++cc) {
        float v = acc[rr][cc] + s_b1[cb * 8 + cc];
        s_d1[(rb * 4 + rr) * 256 + cb * 8 + cc] = (f16)fmaxf(v, 0.f);
      }
  }
  __syncthreads();

  // ---- L2: [32,256] @ [256->128]
  {
    const int rb = tid >> 4;  // 16 row blocks x2
    const int cb = tid & 15;  // 16 col blocks x8
    float acc[2][8];
#pragma unroll
    for (int rr = 0; rr < 2; ++rr)
#pragma unroll
      for (int cc = 0; cc < 8; ++cc) acc[rr][cc] = 0.f;
    for (int ks = 0; ks < 16; ++ks) {
      __syncthreads();
      if (tid < 128) {
        const u32x4* wsrc = (const u32x4*)(w2T + (size_t)tid * 256 + ks * 16);
        u32x2* wdst = (u32x2*)(s_wst + tid * 20);
        u32x4 a = wsrc[0], b = wsrc[1];
        u32x2 p0; p0.x = a.x; p0.y = a.y;
        u32x2 p1; p1.x = a.z; p1.y = a.w;
        u32x2 p2; p2.x = b.x; p2.y = b.y;
        u32x2 p3; p3.x = b.z; p3.y = b.w;
        wdst[0] = p0; wdst[1] = p1; wdst[2] = p2; wdst[3] = p3;
      }
      __syncthreads();
#pragma unroll
      for (int kb = 0; kb < 2; ++kb) {
        u32x4 xv[2];
#pragma unroll
        for (int rr = 0; rr < 2; ++rr)
          xv[rr] = *(const u32x4*)(s_d1 + (rb * 2 + rr) * 256 + ks * 16 + kb * 8);
#pragma unroll
        for (int cc = 0; cc < 8; ++cc) {
          u32x4 wv = ld2x64(s_wst + (cb * 8 + cc) * 20 + kb * 8);
#pragma unroll
          for (int rr = 0; rr < 2; ++rr) acc[rr][cc] = dot8(xv[rr], wv, acc[rr][cc]);
        }
      }
    }
    __syncthreads();
#pragma unroll
    for (int rr = 0; rr < 2; ++rr)
#pragma unroll
      for (int cc = 0; cc < 8; ++cc) {
        float v = acc[rr][cc] + s_b2[cb * 8 + cc];
        s_d2[(rb * 2 + rr) * 128 + cb * 8 + cc] = (f16)fmaxf(v, 0.f);
      }
  }
  __syncthreads();

  // ---- L3: [32,128] @ [128->32] -> out (f32)
  {
    const int r = tid >> 3;  // 32 rows
    const int cg = tid & 7;  // 4 cols each
    float acc[4] = {0.f, 0.f, 0.f, 0.f};
#pragma unroll
    for (int kb = 0; kb < 16; ++kb) {
      u32x4 xv = *(const u32x4*)(s_d2 + r * 128 + kb * 8);
#pragma unroll
      for (int cc = 0; cc < 4; ++cc) {
        u32x4 wv = *(const u32x4*)(s_w3 + (cg * 4 + cc) * 136 + kb * 8);
        acc[cc] = dot8(xv, wv, acc[cc]);
      }
    }
    f32x4 o;
    o.x = acc[0] + s_b3[cg * 4 + 0];
    o.y = acc[1] + s_b3[cg * 4 + 1];
    o.z = acc[2] + s_b3[cg * 4 + 2];
    o.w = acc[3] + s_b3[cg * 4 + 3];
    *(f32x4*)(out + (row0 + r) * 32 + cg * 4) = o;
  }
}

// ---------------------------------------------------------------------------
extern "C" void kernel_launch(void* const* d_in, const int* in_sizes, int n_in,
                              void* d_out, int out_size, void* d_ws, size_t ws_size,
                              hipStream_t stream) {
  const float* seq = (const float*)d_in[0];
  const float* mask = (const float*)d_in[1];
  const float* st = (const float*)d_in[2];
  const float* wx = (const float*)d_in[3];
  const float* wh = (const float*)d_in[4];
  const float* bz = (const float*)d_in[5];
  const float* w1 = (const float*)d_in[6];
  const float* b1 = (const float*)d_in[7];
  const float* w2 = (const float*)d_in[8];
  const float* b2 = (const float*)d_in[9];
  const float* w3 = (const float*)d_in[10];
  const float* b3 = (const float*)d_in[11];
  float* out = (float*)d_out;

  char* ws = (char*)d_ws;
  size_t off = 0;
  auto take = [&](size_t bytes) {
    void* p = ws + off;
    off = (off + bytes + 255) & ~(size_t)255;
    return p;
  };
  f16* wxT = (f16*)take((size_t)G4_ * NIN_ * 2);
  f16* whT = (f16*)take((size_t)G4_ * H_ * 2);
  f16* w1T = (f16*)take((size_t)256 * 256 * 2);
  f16* w2T = (f16*)take((size_t)128 * 256 * 2);
  f16* w3T = (f16*)take((size_t)32 * 128 * 2);
  float* carry = (float*)take((size_t)NTASK * 512 * 4);
  f16* xww = (f16*)take((size_t)P1_WG * CH_ * G4_ * 2);
  f16* hsb = (f16*)take((size_t)NROWS * H_ * 2);
  (void)ws_size; (void)in_sizes; (void)n_in; (void)out_size;

  k_prep<<<dim3(512), dim3(256), 0, stream>>>(wx, wh, w1, w2, w3, wxT, whT, w1T, w2T, w3T);
  k_phase1<<<dim3(P1_WG), dim3(512), 0, stream>>>(seq, mask, wxT, whT, bz, xww, hsb, carry);
  k_phase2<<<dim3(B_), dim3(512), 0, stream>>>(seq, mask, st, wxT, whT, bz, carry, hsb,
                                               out + (size_t)B_ * T_ * 32);
  k_head<<<dim3(NROWS / K3R), dim3(256), 0, stream>>>(hsb, w1T, b1, w2T, b2, w3T, b3, out);
}

// Round 3
// 2678.736 us; speedup vs baseline: 1.0614x; 1.0614x over previous
//
#include <hip/hip_runtime.h>
#include <hip/hip_fp16.h>
#include <stdint.h>

// ---------------------------------------------------------------------------
// StateRNN: masked LSTM (B=64,T=2048,H=256) + 3-layer MLP head.
// R3 design:
//  * phase1: 256 WGs x 512 thr; per WG the full wh (f16) resident as
//    192 VGPRs/thread + 128KB LDS. ALL 2048 (b,chunk) tasks run all 64
//    steps from zero state (keep-masking makes post-reset math exact;
//    pre-reset garbage rows are overwritten by phase2). xw computed in
//    8-step LDS-staged refills (no global round-trip).
//  * __launch_bounds__(512,1): 2nd arg=2 was capping VGPRs at 128 and
//    spilling the 192-reg weight block (R2 counters: VGPR=128, VALUBusy 46%).
//  * phase2: sequential prefix fill per batch row + carry adoption.
//  * head: fused 3-layer f16 MLP (unchanged from R2).
// ---------------------------------------------------------------------------

typedef _Float16 f16;
typedef _Float16 f16x2 __attribute__((ext_vector_type(2)));
typedef unsigned int u32;
typedef u32 u32x2 __attribute__((ext_vector_type(2)));
typedef u32 u32x4 __attribute__((ext_vector_type(4)));
typedef float f32x4 __attribute__((ext_vector_type(4)));

#define B_     64
#define T_     2048
#define NIN_   48
#define H_     256
#define G4_    1024
#define CH_    64
#define NCHUNK (T_ / CH_)       // 32
#define NTASK  (B_ * NCHUNK)    // 2048
#define P1_WG  256
#define P1_TPW (NTASK / P1_WG)  // 8
#define NROWS  (B_ * T_)        // 131072

__device__ __forceinline__ f16x2 as_h2(u32 u) { return __builtin_bit_cast(f16x2, u); }

__device__ __forceinline__ float dot2(u32 a, u32 b, float c) {
#if __has_builtin(__builtin_amdgcn_fdot2)
  return __builtin_amdgcn_fdot2(as_h2(a), as_h2(b), c, false);
#else
  f16x2 ah = as_h2(a), bh = as_h2(b);
  return c + (float)ah.x * (float)bh.x + (float)ah.y * (float)bh.y;
#endif
}

__device__ __forceinline__ float dot8(u32x4 a, u32x4 b, float acc) {
  acc = dot2(a.x, b.x, acc);
  acc = dot2(a.y, b.y, acc);
  acc = dot2(a.z, b.z, acc);
  acc = dot2(a.w, b.w, acc);
  return acc;
}

__device__ __forceinline__ u32x4 ld2x64(const f16* p) {
  u32x2 a = *(const u32x2*)p;
  u32x2 b = *(const u32x2*)(p + 4);
  u32x4 r; r.x = a.x; r.y = a.y; r.z = b.x; r.w = b.y;
  return r;
}

__device__ __forceinline__ float mix8(f32x4 x0, f32x4 x1, u32x4 wv, float acc) {
  f16x2 p;
  p = as_h2(wv.x); acc = fmaf((float)p.x, x0.x, acc); acc = fmaf((float)p.y, x0.y, acc);
  p = as_h2(wv.y); acc = fmaf((float)p.x, x0.z, acc); acc = fmaf((float)p.y, x0.w, acc);
  p = as_h2(wv.z); acc = fmaf((float)p.x, x1.x, acc); acc = fmaf((float)p.y, x1.y, acc);
  p = as_h2(wv.w); acc = fmaf((float)p.x, x1.z, acc); acc = fmaf((float)p.y, x1.w, acc);
  return acc;
}

__device__ __forceinline__ float sigmf(float x) {
  return 1.0f / (1.0f + __builtin_exp2f(-1.44269504f * x));
}
__device__ __forceinline__ float tanhf_(float x) {
  return 2.0f / (1.0f + __builtin_exp2f(-2.88539008f * x)) - 1.0f;
}

// ---------------------------------------------------------------------------
// K0: convert weights to f16, transposed. wxT[c][k] (1024x48),
// whT[c][k] (1024x256), w1T/w2T/w3T for the head.
// ---------------------------------------------------------------------------
__global__ void k_prep(const float* __restrict__ wx, const float* __restrict__ wh,
                       const float* __restrict__ w1, const float* __restrict__ w2,
                       const float* __restrict__ w3,
                       f16* __restrict__ wxT, f16* __restrict__ whT,
                       f16* __restrict__ w1T, f16* __restrict__ w2T,
                       f16* __restrict__ w3T) {
  const int i0 = blockIdx.x * blockDim.x + threadIdx.x;
  const int stride = gridDim.x * blockDim.x;
  for (int idx = i0; idx < NIN_ * G4_; idx += stride) {
    int k = idx / G4_, c = idx % G4_;
    wxT[c * NIN_ + k] = (f16)wx[idx];
  }
  for (int idx = i0; idx < H_ * G4_; idx += stride) {
    int k = idx / G4_, c = idx % G4_;
    whT[c * H_ + k] = (f16)wh[idx];
  }
  for (int idx = i0; idx < 256 * 256; idx += stride) {
    int k = idx / 256, o = idx % 256;
    w1T[o * 256 + k] = (f16)w1[idx];
  }
  for (int idx = i0; idx < 256 * 128; idx += stride) {
    int k = idx / 128, o = idx % 128;
    w2T[o * 256 + k] = (f16)w2[idx];
  }
  for (int idx = i0; idx < 128 * 32; idx += stride) {
    int k = idx / 32, o = idx % 32;
    w3T[o * 128 + k] = (f16)w3[idx];
  }
}

// ---------------------------------------------------------------------------
// Phase 1
// ---------------------------------------------------------------------------
__global__ __launch_bounds__(512, 1) void k_phase1(
    const float* __restrict__ seq, const float* __restrict__ mask,
    const f16* __restrict__ wxT, const f16* __restrict__ whT,
    const float* __restrict__ bias,
    f16* __restrict__ hs, float* __restrict__ carry) {
  __shared__ __attribute__((aligned(16))) u32x4 s_w[4 * 4 * 512];   // 128KB wh LDS share
  __shared__ __attribute__((aligned(16))) f16 s_xw[8 * G4_];        // 16KB xw stage
  __shared__ __attribute__((aligned(16))) f16 s_x[CH_ * NIN_];      // 6KB x chunk
  __shared__ __attribute__((aligned(16))) f16 s_h[2][H_];           // h double buffer
  __shared__ float s_m[CH_];

  const int tid = threadIdx.x;
  const int j = tid >> 1, q = tid & 1;

  // resident wh: per thread 4 gates x 128 k: 12 blocks reg + 4 blocks LDS
  u32x4 wreg[4][12];
#pragma unroll
  for (int g = 0; g < 4; ++g) {
    const f16* wp = whT + (size_t)(g * H_ + j) * H_ + q * 128;
#pragma unroll
    for (int kb = 0; kb < 12; ++kb) wreg[g][kb] = *(const u32x4*)(wp + kb * 8);
#pragma unroll
    for (int kb = 0; kb < 4; ++kb)
      s_w[(g * 4 + kb) * 512 + tid] = *(const u32x4*)(wp + 96 + kb * 8);
  }
  __syncthreads();

  for (int task = 0; task < P1_TPW; ++task) {
    const int gtask = blockIdx.x * P1_TPW + task;
    const int b = gtask >> 5, ch = gtask & 31;
    const int t0 = ch * CH_;

    // stage x chunk (f16), mask chunk, zero h
    {
      const float* sp = seq + ((size_t)b * T_ + t0) * NIN_;
      for (int i = tid; i < CH_ * NIN_; i += 512) s_x[i] = (f16)sp[i];
    }
    if (tid < CH_) s_m[tid] = mask[b * T_ + t0 + tid];
    if (tid < 128) ((u32*)s_h[0])[tid] = 0u;   // avoid NaN-pattern LDS (0*NaN=NaN)
    __syncthreads();

    float c_state = 0.f, h_last = 0.f;

    for (int lt = 0; lt < CH_; ++lt) {
      // ---- every 8 steps: refill s_xw rows [lt, lt+8) = x@wx + b (f16) ----
      if ((lt & 7) == 0) {
        const int c0 = tid * 2;
        float a0[8], a1[8];
        const float b0 = bias[c0], b1v = bias[c0 + 1];
#pragma unroll
        for (int rr = 0; rr < 8; ++rr) { a0[rr] = b0; a1[rr] = b1v; }
#pragma unroll
        for (int kb = 0; kb < 6; ++kb) {
          u32x4 w0 = *(const u32x4*)(wxT + c0 * NIN_ + kb * 8);
          u32x4 w1 = *(const u32x4*)(wxT + (c0 + 1) * NIN_ + kb * 8);
#pragma unroll
          for (int rr = 0; rr < 8; ++rr) {
            u32x4 xv = *(const u32x4*)(&s_x[(lt + rr) * NIN_ + kb * 8]);
            a0[rr] = dot8(xv, w0, a0[rr]);
            a1[rr] = dot8(xv, w1, a1[rr]);
          }
        }
#pragma unroll
        for (int rr = 0; rr < 8; ++rr) {
          f16x2 o2; o2.x = (f16)a0[rr]; o2.y = (f16)a1[rr];
          *(f16x2*)(&s_xw[rr * G4_ + c0]) = o2;
        }
        __syncthreads();
      }

      // ---- recurrent step ----
      const float keep = 1.0f - s_m[lt];
      const int par = lt & 1;
      const f16* hrow = &s_h[par][q * 128];
      float acc[4] = {0.f, 0.f, 0.f, 0.f};
#pragma unroll
      for (int kb = 0; kb < 12; ++kb) {
        u32x4 hv = *(const u32x4*)(hrow + kb * 8);
#pragma unroll
        for (int g = 0; g < 4; ++g) acc[g] = dot8(hv, wreg[g][kb], acc[g]);
      }
#pragma unroll
      for (int kb = 0; kb < 4; ++kb) {
        u32x4 hv = *(const u32x4*)(hrow + 96 + kb * 8);
#pragma unroll
        for (int g = 0; g < 4; ++g)
          acc[g] = dot8(hv, s_w[(g * 4 + kb) * 512 + tid], acc[g]);
      }
#pragma unroll
      for (int g = 0; g < 4; ++g) {
        acc[g] *= keep;                 // uniform within the lane pair
        acc[g] += __shfl_xor(acc[g], 1);
      }
      const f16* xr = &s_xw[(lt & 7) * G4_];
      float z0 = acc[0] + (float)xr[j];
      float z1 = acc[1] + (float)xr[H_ + j];
      float z2 = acc[2] + (float)xr[2 * H_ + j];
      float z3 = acc[3] + (float)xr[3 * H_ + j];
      float ig = sigmf(z0), fg = sigmf(z1), og = sigmf(z2), ug = tanhf_(z3);
      c_state = fg * (keep * c_state) + ig * ug;
      const float hn = og * tanhf_(c_state);
      h_last = hn;
      if (q == 0) {
        s_h[par ^ 1][j] = (f16)hn;
        hs[((size_t)(t0 + lt) * B_ + b) * H_ + j] = (f16)hn;  // time-major
      }
      __syncthreads();
    }
    if (q == 0) {
      carry[(size_t)gtask * 512 + j] = c_state;
      carry[(size_t)gtask * 512 + H_ + j] = h_last;
    }
    __syncthreads();  // all reads of s_x/s_m/s_h done before next task restages
  }
}

// ---------------------------------------------------------------------------
// Phase 2: 64 WGs (one per batch row). Fill prefixes [t0, t0+r) from the true
// carry; adopt phase-1 carry afterwards. Prefix steps have mask==0.
// ---------------------------------------------------------------------------
__global__ __launch_bounds__(512, 1) void k_phase2(
    const float* __restrict__ seq, const float* __restrict__ mask,
    const float* __restrict__ states_in,
    const f16* __restrict__ wxT, const f16* __restrict__ whT,
    const float* __restrict__ bias,
    const float* __restrict__ carry,
    f16* __restrict__ hs, float* __restrict__ out_states) {
  __shared__ __attribute__((aligned(16))) u32x4 s_w[4 * 4 * 512];
  __shared__ __attribute__((aligned(16))) f16 s_h[H_];
  __shared__ __attribute__((aligned(16))) float s_x48[NIN_];
  __shared__ int s_r;

  const int tid = threadIdx.x;
  const int j = tid >> 1, q = tid & 1;
  const int b = blockIdx.x;

  u32x4 wreg[4][12];
#pragma unroll
  for (int g = 0; g < 4; ++g) {
    const f16* wp = whT + (size_t)(g * H_ + j) * H_ + q * 128;
#pragma unroll
    for (int kb = 0; kb < 12; ++kb) wreg[g][kb] = *(const u32x4*)(wp + kb * 8);
#pragma unroll
    for (int kb = 0; kb < 4; ++kb)
      s_w[(g * 4 + kb) * 512 + tid] = *(const u32x4*)(wp + 96 + kb * 8);
  }
  if (tid < H_) s_h[tid] = (f16)states_in[b * 512 + H_ + tid];
  float c_state = states_in[b * 512 + j];
  float h_cur = states_in[b * 512 + H_ + j];
  const float bia[4] = {bias[j], bias[H_ + j], bias[2 * H_ + j], bias[3 * H_ + j]};
  __syncthreads();

  for (int ch = 0; ch < NCHUNK; ++ch) {
    const int t0 = ch * CH_;
    if (tid < 64) {
      float mv = mask[b * T_ + t0 + tid];
      unsigned long long bal = __ballot(mv != 0.0f);
      if (tid == 0) s_r = bal ? (__ffsll((unsigned long long)bal) - 1) : CH_;
    }
    __syncthreads();
    const int r = s_r;

    for (int t = t0; t < t0 + r; ++t) {  // prefix (mask==0 on all these steps)
      if (tid < NIN_) s_x48[tid] = seq[((size_t)b * T_ + t) * NIN_ + tid];
      __syncthreads();
      float acc[4] = {0.f, 0.f, 0.f, 0.f};
      const f16* hrow = &s_h[q * 128];
#pragma unroll
      for (int kb = 0; kb < 12; ++kb) {
        u32x4 hv = *(const u32x4*)(hrow + kb * 8);
#pragma unroll
        for (int g = 0; g < 4; ++g) acc[g] = dot8(hv, wreg[g][kb], acc[g]);
      }
#pragma unroll
      for (int kb = 0; kb < 4; ++kb) {
        u32x4 hv = *(const u32x4*)(hrow + 96 + kb * 8);
#pragma unroll
        for (int g = 0; g < 4; ++g)
          acc[g] = dot8(hv, s_w[(g * 4 + kb) * 512 + tid], acc[g]);
      }
#pragma unroll
      for (int kb = 0; kb < 3; ++kb) {
        f32x4 x0 = *(const f32x4*)(s_x48 + q * 24 + kb * 8);
        f32x4 x1 = *(const f32x4*)(s_x48 + q * 24 + kb * 8 + 4);
#pragma unroll
        for (int g = 0; g < 4; ++g) {
          u32x4 wv = *(const u32x4*)(wxT + (size_t)(g * H_ + j) * NIN_ + q * 24 + kb * 8);
          acc[g] = mix8(x0, x1, wv, acc[g]);
        }
      }
#pragma unroll
      for (int g = 0; g < 4; ++g) acc[g] += __shfl_xor(acc[g], 1);
      float z0 = acc[0] + bia[0], z1 = acc[1] + bia[1];
      float z2 = acc[2] + bia[2], z3 = acc[3] + bia[3];
      float ig = sigmf(z0), fg = sigmf(z1), og = sigmf(z2), ug = tanhf_(z3);
      c_state = fg * c_state + ig * ug;
      const float hn = og * tanhf_(c_state);
      h_cur = hn;
      __syncthreads();
      if (q == 0) {
        s_h[j] = (f16)hn;
        hs[((size_t)t * B_ + b) * H_ + j] = (f16)hn;
      }
      __syncthreads();
    }

    if (r < CH_) {  // adopt exact phase-1 carry
      const int gtask = b * NCHUNK + ch;
      c_state = carry[(size_t)gtask * 512 + j];
      h_cur = carry[(size_t)gtask * 512 + H_ + j];
      __syncthreads();
      if (tid < H_) s_h[tid] = (f16)carry[(size_t)gtask * 512 + H_ + tid];
      __syncthreads();
    }
  }
  if (q == 0) {
    out_states[b * 512 + j] = c_state;
    out_states[b * 512 + H_ + j] = h_cur;
  }
}

// ---------------------------------------------------------------------------
// Head: fused 3-layer MLP over 32-row tiles of flat [T*B, H].
// ---------------------------------------------------------------------------
#define K3R 32
__global__ __launch_bounds__(256, 2) void k_head(
    const f16* __restrict__ hs,
    const f16* __restrict__ w1T, const float* __restrict__ b1,
    const f16* __restrict__ w2T, const float* __restrict__ b2,
    const f16* __restrict__ w3T, const float* __restrict__ b3,
    float* __restrict__ out) {
  __shared__ __attribute__((aligned(16))) f16 s_xx[K3R * 256];
  __shared__ __attribute__((aligned(16))) f16 s_d1[K3R * 256];
  __shared__ __attribute__((aligned(16))) f16 s_d2[K3R * 128];
  __shared__ __attribute__((aligned(16))) f16 s_wst[256 * 20];
  __shared__ __attribute__((aligned(16))) f16 s_w3[32 * 136];
  __shared__ float s_b1[256];
  __shared__ float s_b2[128];
  __shared__ float s_b3[32];

  const int tid = threadIdx.x;
  const size_t row0 = (size_t)blockIdx.x * K3R;

  {
    const u32x4* src = (const u32x4*)(hs + row0 * 256);
    u32x4* dst = (u32x4*)s_xx;
    for (int i = tid; i < K3R * 256 / 8; i += 256) dst[i] = src[i];
  }
  for (int i = tid; i < 32 * 128; i += 256) {
    int c = i / 128, k = i % 128;
    s_w3[c * 136 + k] = w3T[i];
  }
  if (tid < 256) s_b1[tid] = b1[tid];
  if (tid < 128) s_b2[tid] = b2[tid];
  if (tid < 32) s_b3[tid] = b3[tid];

  // ---- L1: [32,256] @ [256->256]
  {
    const int rb = tid >> 5;
    const int cb = tid & 31;
    float acc[4][8];
#pragma unroll
    for (int rr = 0; rr < 4; ++rr)
#pragma unroll
      for (int cc = 0; cc < 8; ++cc) acc[rr][cc] = 0.f;
    for (int ks = 0; ks < 16; ++ks) {
      __syncthreads();
      {
        const u32x4* wsrc = (const u32x4*)(w1T + (size_t)tid * 256 + ks * 16);
        u32x2* wdst = (u32x2*)(s_wst + tid * 20);
        u32x4 a = wsrc[0], b = wsrc[1];
        u32x2 p0; p0.x = a.x; p0.y = a.y;
        u32x2 p1; p1.x = a.z; p1.y = a.w;
        u32x2 p2; p2.x = b.x; p2.y = b.y;
        u32x2 p3; p3.x = b.z; p3.y = b.w;
        wdst[0] = p0; wdst[1] = p1; wdst[2] = p2; wdst[3] = p3;
      }
      __syncthreads();
#pragma unroll
      for (int kb = 0; kb < 2; ++kb) {
        u32x4 xv[4];
#pragma unroll
        for (int rr = 0; rr < 4; ++rr)
          xv[rr] = *(const u32x4*)(s_xx + (rb * 4 + rr) * 256 + ks * 16 + kb * 8);
#pragma unroll
        for (int cc = 0; cc < 8; ++cc) {
          u32x4 wv = ld2x64(s_wst + (cb * 8 + cc) * 20 + kb * 8);
#pragma unroll
          for (int rr = 0; rr < 4; ++rr) acc[rr][cc] = dot8(xv[rr], wv, acc[rr][cc]);
        }
      }
    }
    __syncthreads();
#pragma unroll
    for (int rr = 0; rr < 4; ++rr)
#pragma unroll
      for (int cc = 0; cc < 8; ++cc) {
        float v = acc[rr][cc] + s_b1[cb * 8 + cc];
        s_d1[(rb * 4 + rr) * 256 + cb * 8 + cc] = (f16)fmaxf(v, 0.f);
      }
  }
  __syncthreads();

  // ---- L2: [32,256] @ [256->128]
  {
    const int rb = tid >> 4;
    const int cb = tid & 15;
    float acc[2][8];
#pragma unroll
    for (int rr = 0; rr < 2; ++rr)
#pragma unroll
      for (int cc = 0; cc < 8; ++cc) acc[rr][cc] = 0.f;
    for (int ks = 0; ks < 16; ++ks) {
      __syncthreads();
      if (tid < 128) {
        const u32x4* wsrc = (const u32x4*)(w2T + (size_t)tid * 256 + ks * 16);
        u32x2* wdst = (u32x2*)(s_wst + tid * 20);
        u32x4 a = wsrc[0], b = wsrc[1];
        u32x2 p0; p0.x = a.x; p0.y = a.y;
        u32x2 p1; p1.x = a.z; p1.y = a.w;
        u32x2 p2; p2.x = b.x; p2.y = b.y;
        u32x2 p3; p3.x = b.z; p3.y = b.w;
        wdst[0] = p0; wdst[1] = p1; wdst[2] = p2; wdst[3] = p3;
      }
      __syncthreads();
#pragma unroll
      for (int kb = 0; kb < 2; ++kb) {
        u32x4 xv[2];
#pragma unroll
        for (int rr = 0; rr < 2; ++rr)
          xv[rr] = *(const u32x4*)(s_d1 + (rb * 2 + rr) * 256 + ks * 16 + kb * 8);
#pragma unroll
        for (int cc = 0; cc < 8; ++cc) {
          u32x4 wv = ld2x64(s_wst + (cb * 8 + cc) * 20 + kb * 8);
#pragma unroll
          for (int rr = 0; rr < 2; ++rr) acc[rr][cc] = dot8(xv[rr], wv, acc[rr][cc]);
        }
      }
    }
    __syncthreads();
#pragma unroll
    for (int rr = 0; rr < 2; ++rr)
#pragma unroll
      for (int cc = 0; cc < 8; ++cc) {
        float v = acc[rr][cc] + s_b2[cb * 8 + cc];
        s_d2[(rb * 2 + rr) * 128 + cb * 8 + cc] = (f16)fmaxf(v, 0.f);
      }
  }
  __syncthreads();

  // ---- L3: [32,128] @ [128->32] -> out (f32)
  {
    const int r = tid >> 3;
    const int cg = tid & 7;
    float acc[4] = {0.f, 0.f, 0.f, 0.f};
#pragma unroll
    for (int kb = 0; kb < 16; ++kb) {
      u32x4 xv = *(const u32x4*)(s_d2 + r * 128 + kb * 8);
#pragma unroll
      for (int cc = 0; cc < 4; ++cc) {
        u32x4 wv = *(const u32x4*)(s_w3 + (cg * 4 + cc) * 136 + kb * 8);
        acc[cc] = dot8(xv, wv, acc[cc]);
      }
    }
    f32x4 o;
    o.x = acc[0] + s_b3[cg * 4 + 0];
    o.y = acc[1] + s_b3[cg * 4 + 1];
    o.z = acc[2] + s_b3[cg * 4 + 2];
    o.w = acc[3] + s_b3[cg * 4 + 3];
    *(f32x4*)(out + (row0 + r) * 32 + cg * 4) = o;
  }
}

// ---------------------------------------------------------------------------
extern "C" void kernel_launch(void* const* d_in, const int* in_sizes, int n_in,
                              void* d_out, int out_size, void* d_ws, size_t ws_size,
                              hipStream_t stream) {
  const float* seq = (const float*)d_in[0];
  const float* mask = (const float*)d_in[1];
  const float* st = (const float*)d_in[2];
  const float* wx = (const float*)d_in[3];
  const float* wh = (const float*)d_in[4];
  const float* bz = (const float*)d_in[5];
  const float* w1 = (const float*)d_in[6];
  const float* b1 = (const float*)d_in[7];
  const float* w2 = (const float*)d_in[8];
  const float* b2 = (const float*)d_in[9];
  const float* w3 = (const float*)d_in[10];
  const float* b3 = (const float*)d_in[11];
  float* out = (float*)d_out;

  char* ws = (char*)d_ws;
  size_t off = 0;
  auto take = [&](size_t bytes) {
    void* p = ws + off;
    off = (off + bytes + 255) & ~(size_t)255;
    return p;
  };
  f16* wxT = (f16*)take((size_t)G4_ * NIN_ * 2);
  f16* whT = (f16*)take((size_t)G4_ * H_ * 2);
  f16* w1T = (f16*)take((size_t)256 * 256 * 2);
  f16* w2T = (f16*)take((size_t)128 * 256 * 2);
  f16* w3T = (f16*)take((size_t)32 * 128 * 2);
  float* carry = (float*)take((size_t)NTASK * 512 * 4);
  f16* hsb = (f16*)take((size_t)NROWS * H_ * 2);
  (void)ws_size; (void)in_sizes; (void)n_in; (void)out_size;

  k_prep<<<dim3(512), dim3(256), 0, stream>>>(wx, wh, w1, w2, w3, wxT, whT, w1T, w2T, w3T);
  k_phase1<<<dim3(P1_WG), dim3(512), 0, stream>>>(seq, mask, wxT, whT, bz, hsb, carry);
  k_phase2<<<dim3(B_), dim3(512), 0, stream>>>(seq, mask, st, wxT, whT, bz, carry, hsb,
                                               out + (size_t)B_ * T_ * 32);
  k_head<<<dim3(NROWS / K3R), dim3(256), 0, stream>>>(hsb, w1T, b1, w2T, b2, w3T, b3, out);
}